// Round 12
// baseline (225.209 us; speedup 1.0000x reference)
//
#include <hip/hip_runtime.h>
#include <stdint.h>

#define FN 16
#define FD 32
#define KC 16
#define BS 256
#define TS 48
#define CS 3000
#define VV 18
#define NW 96           // padded uint32 words per bit-row (94 used for 3000 bits)
#define NEG_BIG 10000000.0f

// ---------------- Kernel A: VQ codes — j-uniform blocks, LDS-transposed x, scalar cen ----------------
__global__ __launch_bounds__(64) void k_codes(const float* __restrict__ tdata,
                                              const int* __restrict__ f_mask,
                                              const float* __restrict__ centers,
                                              uint8_t* __restrict__ codes) {
    __shared__ float xs[64][33];
    __shared__ float cns[KC];
    int t   = threadIdx.x;
    int bid = blockIdx.x;
    int j   = bid & 15;
    int n0  = (bid >> 4) << 6;

    const float* cen = centers + (size_t)j * KC * FD;   // block-uniform -> scalar loads

    if (t < KC) {
        float cn = 0.f;
#pragma unroll
        for (int d = 0; d < FD; d++) { float cv = cen[t * FD + d]; cn += cv * cv; }
        cns[t] = cn;
    }
#pragma unroll
    for (int it = 0; it < 8; ++it) {
        int f = t + (it << 6);
        int row = f >> 3, q = f & 7;
        float4 v = *reinterpret_cast<const float4*>(
            tdata + ((size_t)(n0 + row) * FN + j) * FD + (q << 2));
        xs[row][(q << 2) + 0] = v.x;
        xs[row][(q << 2) + 1] = v.y;
        xs[row][(q << 2) + 2] = v.z;
        xs[row][(q << 2) + 3] = v.w;
    }
    __syncthreads();

    float xv[FD];
#pragma unroll
    for (int d = 0; d < FD; d++) xv[d] = xs[t][d];

    float best = 3.4e38f; int bestk = 0;
    for (int k = 0; k < KC; k++) {
        float dot = 0.f;
#pragma unroll
        for (int d = 0; d < FD; d++) dot += xv[d] * cen[k * FD + d];
        float dist = cns[k] - 2.f * dot;     // ||x||^2 omitted: argmin-invariant
        if (dist < best) { best = dist; bestk = k; }   // first-min wins
    }
    int idx = (n0 + t) * FN + j;
    codes[idx] = f_mask[idx] ? (uint8_t)(bestk + 2) : (uint8_t)1;
}

// ---------------- Kernel B: bit-pack patterns — LDS-staged, p[] in regs, coalesced ----------------
__global__ __launch_bounds__(128) void k_buildM(const int* __restrict__ pat,
                                                uint32_t* __restrict__ M) {
    __shared__ int pl[256 * 17];
    int tid = threadIdx.x;
    int i  = blockIdx.x / 12;
    int ch = blockIdx.x % 12;
    int c0 = ch << 8;

    for (int f = tid; f < 256 * 16; f += 128) {
        int r = f >> 4, jj = f & 15;
        int c = c0 + r;
        pl[r * 17 + jj] = (c < CS) ? pat[((size_t)i * CS + c) * FN + jj] : -1;
    }
    __syncthreads();

    int w = tid >> 4, j = tid & 15;
    int p[32];
#pragma unroll
    for (int cb = 0; cb < 32; cb++) p[cb] = pl[((w << 5) + cb) * 17 + j];

    uint32_t w0 = 0u;
#pragma unroll
    for (int cb = 0; cb < 32; cb++) w0 |= (p[cb] == 0) ? (1u << cb) : 0u;

    uint32_t* dst = M + ((size_t)((i << 4) | j) * VV) * NW + (ch << 3) + w;
#pragma unroll
    for (int v = 0; v < VV; v++) {
        uint32_t wv = w0;
#pragma unroll
        for (int cb = 0; cb < 32; cb++) wv |= (p[cb] == v) ? (1u << cb) : 0u;
        dst[(size_t)v * NW] = wv;
    }
}

// ---------------- Kernel C: pm per (i,b) — t-chunks of 16, per-lane dead-skip, 96 thr ----------------
// Lane-packed cs (lo=t<32, hi=t>=32) keeps readlane sources < 32 so the half-wave (tid 64..95) works.
__global__ __launch_bounds__(96) void k_match(const uint8_t* __restrict__ codes,
                                              const uint32_t* __restrict__ M,
                                              uint32_t* __restrict__ pm) {
    int b = blockIdx.x & 255;
    int i = blockIdx.x >> 8;
    int tid = threadIdx.x;                // 0..95, all store
    __shared__ uint16_t cs16[FN][TS];     // [j][t] = v * 384 (byte offset of row v)

    for (int f = tid; f < TS * FN; f += 96) {
        int t = f >> 4, jj = f & 15;
        cs16[jj][t] = (uint16_t)codes[(size_t)b * TS * FN + f] * (uint16_t)(NW * 4);
    }
    __syncthreads();

    int l31 = tid & 31;
    const char* Mi = (const char*)(M + (size_t)i * FN * VV * NW);
    size_t cgb = (size_t)tid << 2;        // this thread's word offset within a row
    uint32_t acc = 0;

#pragma unroll
    for (int ch = 0; ch < 3; ch++) {      // t = ch*16 .. ch*16+15
        uint32_t m[16];
#pragma unroll
        for (int t = 0; t < 16; t++) m[t] = 0xFFFFFFFFu;

        for (int j = 0; j < FN; j++) {
            // packed per-lane cs: lanes 0..31 carry lo = cs[j][l31], lanes 0..15 also hi = cs[j][32+l31]
            uint32_t vvp = (uint32_t)cs16[j][l31];
            if (l31 < 16) vvp |= ((uint32_t)cs16[j][32 + l31]) << 16;
            const char* page = Mi + (size_t)j * (VV * NW * 4);
            uint32_t any = 0;
#pragma unroll
            for (int t = 0; t < 16; t++) {
                int gt = ch * 16 + t;     // global t, compile-time per unroll
                int src = (gt < 32) ? gt : (gt - 32);
                uint32_t r = (uint32_t)__builtin_amdgcn_readlane((int)vvp, src);
                uint32_t sv = (gt < 32) ? (r & 0xFFFFu) : (r >> 16);
                if (m[t]) m[t] &= *(const uint32_t*)(page + sv + cgb);  // exec-masked: dead lanes fetch nothing
                any |= m[t];
            }
            if (__ballot(any != 0u) == 0ULL) break;   // per-wave chunk exit
        }
#pragma unroll
        for (int t = 0; t < 16; t++) acc |= m[t];
    }

    pm[(size_t)blockIdx.x * NW + tid] = acc;
}

// ---------------- Kernel E: per-(i,b) attention + rep (anymask folded in) ----------------
__global__ __launch_bounds__(256) void k_attn(
    const float* __restrict__ tdata, const float* __restrict__ pat_rep,
    const float* __restrict__ pos_cnt, const float* __restrict__ neg_cnt,
    const float* __restrict__ W_q, const float* __restrict__ b_q,
    const float* __restrict__ W_k, const float* __restrict__ b_k,
    const float* __restrict__ W_v, const float* __restrict__ b_v,
    const uint32_t* __restrict__ pm, const int* __restrict__ f_mask,
    float* __restrict__ out_a, float* __restrict__ out_rep)
{
    int b = blockIdx.x & 255;
    int i = blockIdx.x >> 8;
    int tid = threadIdx.x;

    __shared__ float e_s[CS];
    __shared__ float iq_s[FD];
    __shared__ float kq_s[FD + 1];
    __shared__ float s_sh[FD + 1];
    __shared__ float red[4];
    __shared__ float bkiq_s, maxv_s, sum_s;
    __shared__ int any_s;

    int mbit = (tid < TS) ? f_mask[((size_t)b * TS + tid) * FN + i] : 0;
    unsigned long long bal = __ballot(mbit != 0);
    if (tid == 0) any_s = (bal != 0ULL);

    const float* q = tdata + (((size_t)b * TS + (TS - 1)) * FN + i) * FD;
    if (tid >= 64 && tid < 64 + FD) {
        int r = tid - 64;
        float acc = b_q[i * FD + r];
        const float* Wr = W_q + ((size_t)i * FD + r) * FD;
#pragma unroll
        for (int e = 0; e < FD; e++) acc += q[e] * Wr[e];
        iq_s[r] = acc;
    }
    if (tid < FD + 1) s_sh[tid] = 0.f;
    __syncthreads();
    if (tid < FD + 1) {
        float acc = 0.f;
        for (int d = 0; d < FD; d++)
            acc += W_k[((size_t)i * FD + d) * (FD + 1) + tid] * iq_s[d];
        kq_s[tid] = acc;
    }
    if (tid == 64) {
        float acc = 0.f;
        for (int d = 0; d < FD; d++) acc += b_k[i * FD + d] * iq_s[d];
        bkiq_s = acc;
    }
    __syncthreads();
    float bkiq = bkiq_s;

    const uint32_t* pmrow = pm + (size_t)blockIdx.x * NW;

    float lmax = -3.4e38f;
    for (int c = tid; c < CS; c += 256) {
        uint32_t bit = (pmrow[c >> 5] >> (c & 31)) & 1u;
        float e;
        if (bit) {
            const float* pr = pat_rep + ((size_t)i * CS + c) * FD;
            float acc = 0.f;
#pragma unroll
            for (int d = 0; d < FD; d++) acc += pr[d] * kq_s[d];
            float pc = pos_cnt[(size_t)i * CS + c], nc = neg_cnt[(size_t)i * CS + c];
            float ratio = pc / (pc + nc + 1e-6f);
            e = bkiq + acc + ratio * kq_s[FD];
        } else {
            e = bkiq - NEG_BIG;
        }
        e_s[c] = e;
        lmax = fmaxf(lmax, e);
    }
    for (int off = 32; off > 0; off >>= 1) lmax = fmaxf(lmax, __shfl_down(lmax, off));
    if ((tid & 63) == 0) red[tid >> 6] = lmax;
    __syncthreads();
    if (tid == 0) {
        float m = red[0];
        for (int w = 1; w < 4; w++) m = fmaxf(m, red[w]);
        maxv_s = m;
    }
    __syncthreads();
    float maxv = maxv_s;

    float lsum = 0.f;
    for (int c = tid; c < CS; c += 256) {
        float ex = __expf(e_s[c] - maxv);
        e_s[c] = ex;
        lsum += ex;
    }
    for (int off = 32; off > 0; off >>= 1) lsum += __shfl_down(lsum, off);
    if ((tid & 63) == 0) red[tid >> 6] = lsum;
    __syncthreads();
    if (tid == 0) sum_s = red[0] + red[1] + red[2] + red[3];
    __syncthreads();
    float sum = sum_s;

    float* arow = out_a + (size_t)blockIdx.x * CS;
    for (int c = tid; c < CS; c += 256) {
        float a = e_s[c] / sum;
        arow[c] = a;
        uint32_t bit = (pmrow[c >> 5] >> (c & 31)) & 1u;
        if (bit) {
            const float* pr = pat_rep + ((size_t)i * CS + c) * FD;
            for (int f = 0; f < FD; f++) atomicAdd(&s_sh[f], a * pr[f]);
            float pc = pos_cnt[(size_t)i * CS + c], nc = neg_cnt[(size_t)i * CS + c];
            float ratio = pc / (pc + nc + 1e-6f);
            atomicAdd(&s_sh[FD], a * ratio);
        }
    }
    __syncthreads();

    if (tid < FD + 1) {
        float acc = b_v[(size_t)i * (FD + 1) + tid];
        const float* Wr = W_v + ((size_t)i * (FD + 1) + tid) * (FD + 1);
#pragma unroll
        for (int f = 0; f < FD + 1; f++) acc += Wr[f] * s_sh[f];
        float r = any_s ? acc : 0.f;
        out_rep[((size_t)b * FN + i) * (FD + 1) + tid] = r;
    }
}

// ---------------- Kernel F: cali = rep_flat @ W_pred.T  (one block per b) ----------------
__global__ __launch_bounds__(256) void k_cali(const float* __restrict__ rep,
                                              const float* __restrict__ W_pred,
                                              float* __restrict__ out) {
    int b = blockIdx.x;
    int tid = threadIdx.x;
    const int KK = FN * (FD + 1);  // 528
    float a0 = 0.f, a1 = 0.f;
    for (int k = tid; k < KK; k += 256) {
        float r = rep[(size_t)b * KK + k];
        a0 += r * W_pred[k];
        a1 += r * W_pred[KK + k];
    }
    for (int off = 32; off > 0; off >>= 1) {
        a0 += __shfl_down(a0, off);
        a1 += __shfl_down(a1, off);
    }
    __shared__ float r0[4], r1[4];
    if ((tid & 63) == 0) { r0[tid >> 6] = a0; r1[tid >> 6] = a1; }
    __syncthreads();
    if (tid == 0) {
        out[b * 2 + 0] = r0[0] + r0[1] + r0[2] + r0[3];
        out[b * 2 + 1] = r1[0] + r1[1] + r1[2] + r1[3];
    }
}

extern "C" void kernel_launch(void* const* d_in, const int* in_sizes, int n_in,
                              void* d_out, int out_size, void* d_ws, size_t ws_size,
                              hipStream_t stream) {
    const float* tdata   = (const float*)d_in[0];
    const int*   f_mask  = (const int*)d_in[1];     // bool -> int32 on device
    const float* centers = (const float*)d_in[2];
    const int*   pat     = (const int*)d_in[3];
    const float* pat_rep = (const float*)d_in[4];
    const float* pos_cnt = (const float*)d_in[5];
    const float* neg_cnt = (const float*)d_in[6];
    const float* W_q     = (const float*)d_in[7];
    const float* b_q     = (const float*)d_in[8];
    const float* W_k     = (const float*)d_in[9];
    const float* b_k     = (const float*)d_in[10];
    const float* W_v     = (const float*)d_in[11];
    const float* b_v     = (const float*)d_in[12];
    const float* W_pred  = (const float*)d_in[13];

    float* out = (float*)d_out;
    float* out_cali = out;                       // (256, 2)
    float* out_a    = out + 512;                 // (16, 256, 3000)
    float* out_rep  = out + 512 + FN * BS * CS;  // (256, 16, 33)

    char* ws = (char*)d_ws;
    uint8_t*  codes = (uint8_t*)ws;                               // 196608 B
    uint32_t* M     = (uint32_t*)(ws + 200704);                   // 1769472 B
    uint32_t* pm    = (uint32_t*)(ws + 200704 + 1769472);         // 1572864 B

    hipLaunchKernelGGL(k_codes,   dim3(16 * 192), dim3(64), 0, stream,
                       tdata, f_mask, centers, codes);
    hipLaunchKernelGGL(k_buildM,  dim3(16 * 12), dim3(128), 0, stream,
                       pat, M);
    hipLaunchKernelGGL(k_match,   dim3(FN * BS), dim3(96), 0, stream,
                       codes, M, pm);
    hipLaunchKernelGGL(k_attn,    dim3(FN * BS), dim3(256), 0, stream,
                       tdata, pat_rep, pos_cnt, neg_cnt, W_q, b_q, W_k, b_k, W_v, b_v,
                       pm, f_mask, out_a, out_rep);
    hipLaunchKernelGGL(k_cali,    dim3(BS), dim3(256), 0, stream,
                       out_rep, W_pred, out_cali);
}

// Round 13
// 205.610 us; speedup vs baseline: 1.0953x; 1.0953x over previous
//
#include <hip/hip_runtime.h>
#include <stdint.h>

#define FN 16
#define FD 32
#define KC 16
#define BS 256
#define TS 48
#define CS 3000
#define VV 18
#define NW 96           // padded uint32 words per bit-row (94 used for 3000 bits)
#define NEG_BIG 10000000.0f

// ---------------- Kernel A: VQ codes — j-uniform blocks, LDS-transposed x, scalar cen ----------------
__global__ __launch_bounds__(64) void k_codes(const float* __restrict__ tdata,
                                              const int* __restrict__ f_mask,
                                              const float* __restrict__ centers,
                                              uint8_t* __restrict__ codes) {
    __shared__ float xs[64][33];
    __shared__ float cns[KC];
    int t   = threadIdx.x;
    int bid = blockIdx.x;
    int j   = bid & 15;
    int n0  = (bid >> 4) << 6;

    const float* cen = centers + (size_t)j * KC * FD;   // block-uniform -> scalar loads

    if (t < KC) {
        float cn = 0.f;
#pragma unroll
        for (int d = 0; d < FD; d++) { float cv = cen[t * FD + d]; cn += cv * cv; }
        cns[t] = cn;
    }
#pragma unroll
    for (int it = 0; it < 8; ++it) {
        int f = t + (it << 6);
        int row = f >> 3, q = f & 7;
        float4 v = *reinterpret_cast<const float4*>(
            tdata + ((size_t)(n0 + row) * FN + j) * FD + (q << 2));
        xs[row][(q << 2) + 0] = v.x;
        xs[row][(q << 2) + 1] = v.y;
        xs[row][(q << 2) + 2] = v.z;
        xs[row][(q << 2) + 3] = v.w;
    }
    __syncthreads();

    float xv[FD];
#pragma unroll
    for (int d = 0; d < FD; d++) xv[d] = xs[t][d];

    float best = 3.4e38f; int bestk = 0;
    for (int k = 0; k < KC; k++) {
        float dot = 0.f;
#pragma unroll
        for (int d = 0; d < FD; d++) dot += xv[d] * cen[k * FD + d];
        float dist = cns[k] - 2.f * dot;     // ||x||^2 omitted: argmin-invariant
        if (dist < best) { best = dist; bestk = k; }   // first-min wins
    }
    int idx = (n0 + t) * FN + j;
    codes[idx] = f_mask[idx] ? (uint8_t)(bestk + 2) : (uint8_t)1;
}

// ---------------- Kernel B: bit-pack patterns — r7 version: cg-major, coalesced STORES ----------------
__global__ __launch_bounds__(64) void k_buildM(const int* __restrict__ pat,
                                               uint32_t* __restrict__ M) {
    int idx = blockIdx.x * 64 + threadIdx.x;   // (i*16+j)*NW + cg
    if (idx >= FN * FN * NW) return;
    int cg = idx % NW;
    int ij = idx / NW;
    int j = ij & 15, i = ij >> 4;
    int c0 = cg * 32;
    int p[32];                                  // static-indexed -> registers
#pragma unroll
    for (int cb = 0; cb < 32; cb++) {
        int c = c0 + cb;
        p[cb] = (c < CS) ? pat[((size_t)i * CS + c) * FN + j] : -1;
    }
    uint32_t w0 = 0u;                           // wildcard bits
#pragma unroll
    for (int cb = 0; cb < 32; cb++) w0 |= (p[cb] == 0) ? (1u << cb) : 0u;
    uint32_t* dst = M + (size_t)ij * VV * NW + cg;
#pragma unroll
    for (int v = 0; v < VV; v++) {
        uint32_t w = w0;
#pragma unroll
        for (int cb = 0; cb < 32; cb++) w |= (p[cb] == v) ? (1u << cb) : 0u;
        dst[(size_t)v * NW] = w;                // lanes = consecutive cg -> coalesced
    }
}

// ---------------- Kernel C: pm per (i,b) — 1 wave, uint64 words, dead-skip, single j-loop ----------------
__global__ __launch_bounds__(64) void k_match(const uint8_t* __restrict__ codes,
                                              const uint32_t* __restrict__ M,
                                              uint32_t* __restrict__ pm) {
    int b = blockIdx.x & 255;
    int i = blockIdx.x >> 8;
    int lane = threadIdx.x;               // 0..63; lanes 0..47 own words [2l, 2l+1]
    __shared__ uint16_t cs16[FN][TS];     // [j][t] = v * 384 (byte offset of row v)

    for (int f = lane; f < TS * FN; f += 64) {
        int t = f >> 4, jj = f & 15;
        cs16[jj][t] = (uint16_t)codes[(size_t)b * TS * FN + f] * (uint16_t)(NW * 4);
    }
    __syncthreads();

    uint64_t m[TS];
#pragma unroll
    for (int t = 0; t < TS; t++) m[t] = (lane < TS) ? ~0ULL : 0ULL;  // lanes>=48 self-kill

    const char* Mi = (const char*)(M + (size_t)i * FN * VV * NW);
    size_t lb = (size_t)lane << 3;        // byte offset of this lane's 2 words

    for (int j = 0; j < FN; j++) {
        int vv = (lane < TS) ? (int)cs16[j][lane] : 0;   // lane t holds cs[j][t]
        const char* page = Mi + (size_t)j * (VV * NW * 4);
        uint64_t any = 0;
#pragma unroll
        for (int t = 0; t < TS; t++) {
            int sv = __builtin_amdgcn_readlane(vv, t);   // SGPR row byte-offset
            if (m[t]) m[t] &= *(const uint64_t*)(page + sv + lb);  // exec-masked 8B load
            any |= m[t];
        }
        if (__ballot(any != 0ULL) == 0ULL) break;        // whole-wave early exit
    }

    uint64_t acc = 0;
#pragma unroll
    for (int t = 0; t < TS; t++) acc |= m[t];
    if (lane < TS) ((uint64_t*)(pm + (size_t)blockIdx.x * NW))[lane] = acc;
}

// ---------------- Kernel E: per-(i,b) attention + rep (anymask folded in) ----------------
__global__ __launch_bounds__(256) void k_attn(
    const float* __restrict__ tdata, const float* __restrict__ pat_rep,
    const float* __restrict__ pos_cnt, const float* __restrict__ neg_cnt,
    const float* __restrict__ W_q, const float* __restrict__ b_q,
    const float* __restrict__ W_k, const float* __restrict__ b_k,
    const float* __restrict__ W_v, const float* __restrict__ b_v,
    const uint32_t* __restrict__ pm, const int* __restrict__ f_mask,
    float* __restrict__ out_a, float* __restrict__ out_rep)
{
    int b = blockIdx.x & 255;
    int i = blockIdx.x >> 8;
    int tid = threadIdx.x;

    __shared__ float e_s[CS];
    __shared__ float iq_s[FD];
    __shared__ float kq_s[FD + 1];
    __shared__ float s_sh[FD + 1];
    __shared__ float red[4];
    __shared__ float bkiq_s, maxv_s, sum_s;
    __shared__ int any_s;

    int mbit = (tid < TS) ? f_mask[((size_t)b * TS + tid) * FN + i] : 0;
    unsigned long long bal = __ballot(mbit != 0);
    if (tid == 0) any_s = (bal != 0ULL);

    const float* q = tdata + (((size_t)b * TS + (TS - 1)) * FN + i) * FD;
    if (tid >= 64 && tid < 64 + FD) {
        int r = tid - 64;
        float acc = b_q[i * FD + r];
        const float* Wr = W_q + ((size_t)i * FD + r) * FD;
#pragma unroll
        for (int e = 0; e < FD; e++) acc += q[e] * Wr[e];
        iq_s[r] = acc;
    }
    if (tid < FD + 1) s_sh[tid] = 0.f;
    __syncthreads();
    if (tid < FD + 1) {
        float acc = 0.f;
        for (int d = 0; d < FD; d++)
            acc += W_k[((size_t)i * FD + d) * (FD + 1) + tid] * iq_s[d];
        kq_s[tid] = acc;
    }
    if (tid == 64) {
        float acc = 0.f;
        for (int d = 0; d < FD; d++) acc += b_k[i * FD + d] * iq_s[d];
        bkiq_s = acc;
    }
    __syncthreads();
    float bkiq = bkiq_s;

    const uint32_t* pmrow = pm + (size_t)blockIdx.x * NW;

    float lmax = -3.4e38f;
    for (int c = tid; c < CS; c += 256) {
        uint32_t bit = (pmrow[c >> 5] >> (c & 31)) & 1u;
        float e;
        if (bit) {
            const float* pr = pat_rep + ((size_t)i * CS + c) * FD;
            float acc = 0.f;
#pragma unroll
            for (int d = 0; d < FD; d++) acc += pr[d] * kq_s[d];
            float pc = pos_cnt[(size_t)i * CS + c], nc = neg_cnt[(size_t)i * CS + c];
            float ratio = pc / (pc + nc + 1e-6f);
            e = bkiq + acc + ratio * kq_s[FD];
        } else {
            e = bkiq - NEG_BIG;
        }
        e_s[c] = e;
        lmax = fmaxf(lmax, e);
    }
    for (int off = 32; off > 0; off >>= 1) lmax = fmaxf(lmax, __shfl_down(lmax, off));
    if ((tid & 63) == 0) red[tid >> 6] = lmax;
    __syncthreads();
    if (tid == 0) {
        float m = red[0];
        for (int w = 1; w < 4; w++) m = fmaxf(m, red[w]);
        maxv_s = m;
    }
    __syncthreads();
    float maxv = maxv_s;

    float lsum = 0.f;
    for (int c = tid; c < CS; c += 256) {
        float ex = __expf(e_s[c] - maxv);
        e_s[c] = ex;
        lsum += ex;
    }
    for (int off = 32; off > 0; off >>= 1) lsum += __shfl_down(lsum, off);
    if ((tid & 63) == 0) red[tid >> 6] = lsum;
    __syncthreads();
    if (tid == 0) sum_s = red[0] + red[1] + red[2] + red[3];
    __syncthreads();
    float sum = sum_s;

    float* arow = out_a + (size_t)blockIdx.x * CS;
    for (int c = tid; c < CS; c += 256) {
        float a = e_s[c] / sum;
        arow[c] = a;
        uint32_t bit = (pmrow[c >> 5] >> (c & 31)) & 1u;
        if (bit) {
            const float* pr = pat_rep + ((size_t)i * CS + c) * FD;
            for (int f = 0; f < FD; f++) atomicAdd(&s_sh[f], a * pr[f]);
            float pc = pos_cnt[(size_t)i * CS + c], nc = neg_cnt[(size_t)i * CS + c];
            float ratio = pc / (pc + nc + 1e-6f);
            atomicAdd(&s_sh[FD], a * ratio);
        }
    }
    __syncthreads();

    if (tid < FD + 1) {
        float acc = b_v[(size_t)i * (FD + 1) + tid];
        const float* Wr = W_v + ((size_t)i * (FD + 1) + tid) * (FD + 1);
#pragma unroll
        for (int f = 0; f < FD + 1; f++) acc += Wr[f] * s_sh[f];
        float r = any_s ? acc : 0.f;
        out_rep[((size_t)b * FN + i) * (FD + 1) + tid] = r;
    }
}

// ---------------- Kernel F: cali = rep_flat @ W_pred.T  (one block per b) ----------------
__global__ __launch_bounds__(256) void k_cali(const float* __restrict__ rep,
                                              const float* __restrict__ W_pred,
                                              float* __restrict__ out) {
    int b = blockIdx.x;
    int tid = threadIdx.x;
    const int KK = FN * (FD + 1);  // 528
    float a0 = 0.f, a1 = 0.f;
    for (int k = tid; k < KK; k += 256) {
        float r = rep[(size_t)b * KK + k];
        a0 += r * W_pred[k];
        a1 += r * W_pred[KK + k];
    }
    for (int off = 32; off > 0; off >>= 1) {
        a0 += __shfl_down(a0, off);
        a1 += __shfl_down(a1, off);
    }
    __shared__ float r0[4], r1[4];
    if ((tid & 63) == 0) { r0[tid >> 6] = a0; r1[tid >> 6] = a1; }
    __syncthreads();
    if (tid == 0) {
        out[b * 2 + 0] = r0[0] + r0[1] + r0[2] + r0[3];
        out[b * 2 + 1] = r1[0] + r1[1] + r1[2] + r1[3];
    }
}

extern "C" void kernel_launch(void* const* d_in, const int* in_sizes, int n_in,
                              void* d_out, int out_size, void* d_ws, size_t ws_size,
                              hipStream_t stream) {
    const float* tdata   = (const float*)d_in[0];
    const int*   f_mask  = (const int*)d_in[1];     // bool -> int32 on device
    const float* centers = (const float*)d_in[2];
    const int*   pat     = (const int*)d_in[3];
    const float* pat_rep = (const float*)d_in[4];
    const float* pos_cnt = (const float*)d_in[5];
    const float* neg_cnt = (const float*)d_in[6];
    const float* W_q     = (const float*)d_in[7];
    const float* b_q     = (const float*)d_in[8];
    const float* W_k     = (const float*)d_in[9];
    const float* b_k     = (const float*)d_in[10];
    const float* W_v     = (const float*)d_in[11];
    const float* b_v     = (const float*)d_in[12];
    const float* W_pred  = (const float*)d_in[13];

    float* out = (float*)d_out;
    float* out_cali = out;                       // (256, 2)
    float* out_a    = out + 512;                 // (16, 256, 3000)
    float* out_rep  = out + 512 + FN * BS * CS;  // (256, 16, 33)

    char* ws = (char*)d_ws;
    uint8_t*  codes = (uint8_t*)ws;                               // 196608 B
    uint32_t* M     = (uint32_t*)(ws + 200704);                   // 1769472 B
    uint32_t* pm    = (uint32_t*)(ws + 200704 + 1769472);         // 1572864 B

    hipLaunchKernelGGL(k_codes,   dim3(16 * 192), dim3(64), 0, stream,
                       tdata, f_mask, centers, codes);
    hipLaunchKernelGGL(k_buildM,  dim3((FN * FN * NW) / 64), dim3(64), 0, stream,
                       pat, M);
    hipLaunchKernelGGL(k_match,   dim3(FN * BS), dim3(64), 0, stream,
                       codes, M, pm);
    hipLaunchKernelGGL(k_attn,    dim3(FN * BS), dim3(256), 0, stream,
                       tdata, pat_rep, pos_cnt, neg_cnt, W_q, b_q, W_k, b_k, W_v, b_v,
                       pm, f_mask, out_a, out_rep);
    hipLaunchKernelGGL(k_cali,    dim3(BS), dim3(256), 0, stream,
                       out_rep, W_pred, out_cali);
}